// Round 15
// baseline (254.929 us; speedup 1.0000x reference)
//
#include <hip/hip_runtime.h>
#include <stdint.h>

#define NLVL 127.0f
#define NPOS (64 * 289)

typedef int v4i __attribute__((ext_vector_type(4)));
typedef int v16i __attribute__((ext_vector_type(16)));
typedef unsigned int uint;

// bijective XCD-aware swizzle (m204): xcd = bid%8 gets a contiguous work range
__device__ __forceinline__ int swz_wg(int bid, int nwg) {
    const int q = nwg >> 3, r = nwg & 7;
    const int xcd = bid & 7;
    const int base = xcd < r ? xcd * (q + 1) : r * (q + 1) + (xcd - r) * q;
    return base + (bid >> 3);
}

// -------- global abs-max reduction (atomicMax on float bits; values >= 0) ----
__global__ __launch_bounds__(256) void amax_abs_kernel(const float* __restrict__ x,
                                                       int n, float* __restrict__ slot) {
    __shared__ float red[256];
    float lm = 0.f;
    for (int i = blockIdx.x * 256 + threadIdx.x; i < n; i += gridDim.x * 256)
        lm = fmaxf(lm, fabsf(x[i]));
    red[threadIdx.x] = lm;
    __syncthreads();
    for (int s = 128; s > 0; s >>= 1) {
        if (threadIdx.x < s) red[threadIdx.x] = fmaxf(red[threadIdx.x], red[threadIdx.x + s]);
        __syncthreads();
    }
    if (threadIdx.x == 0) atomicMax((unsigned int*)slot, __float_as_uint(red[0]));
}

// -------- quantize input x: NCHW fp32 -> slab int8 [c16][NPOS][16] -----------
__global__ __launch_bounds__(256) void quant_x_kernel(const float* __restrict__ x,
                                                      signed char* __restrict__ n0,
                                                      const float* __restrict__ scal) {
    __shared__ uint t32[64][97];
    const float s = scal[0] / NLVL;
    const int tid = threadIdx.x;
    const int pi = tid & 63;
    const int pos = blockIdx.x * 64 + pi;
    const int n = pos / 289;
    const int hw = pos - n * 289;
    const float* xb = x + (size_t)n * 384 * 289 + hw;
    for (int cq = tid >> 6; cq < 96; cq += 4) {
        uint pk = 0;
#pragma unroll
        for (int k = 0; k < 4; ++k) {
            const float f = xb[(size_t)(cq * 4 + k) * 289];
            float q = rintf(f / s);
            q = fminf(fmaxf(q, -128.f), 127.f);
            pk |= ((uint)((int)q & 0xff)) << (8 * k);
        }
        t32[pi][cq] = pk;
    }
    __syncthreads();
    for (int k = 0; k < 6; ++k) {
        const int c16 = (tid >> 6) + k * 4;  // 0..23
        uint4 v;
        v.x = t32[pi][c16 * 4 + 0];
        v.y = t32[pi][c16 * 4 + 1];
        v.z = t32[pi][c16 * 4 + 2];
        v.w = t32[pi][c16 * 4 + 3];
        *(uint4*)&n0[((size_t)c16 * NPOS + pos) * 16] = v;
    }
}

// -------- merged weight prep: all 4 stages, NO scal dependency ----------------
// quantizes folded weights into wstg [r*GPT + (i>>4)][OCP][16]; stores per-oc
// w_sf and folded bias bf (csf/bq computed later inside the conv prologue).
__global__ __launch_bounds__(256) void wq_kernel(
    const float* __restrict__ w1, const float* __restrict__ g1, const float* __restrict__ b1,
    const float* __restrict__ m1, const float* __restrict__ v1, signed char* __restrict__ s1w,
    float* __restrict__ s1sf, float* __restrict__ s1bf,
    const float* __restrict__ w2, const float* __restrict__ g2, const float* __restrict__ b2,
    const float* __restrict__ m2, const float* __restrict__ v2, signed char* __restrict__ s2w,
    float* __restrict__ s2sf, float* __restrict__ s2bf,
    const float* __restrict__ w3, const float* __restrict__ g3, const float* __restrict__ b3,
    const float* __restrict__ m3, const float* __restrict__ v3, signed char* __restrict__ s3w,
    float* __restrict__ s3sf, float* __restrict__ s3bf,
    const float* __restrict__ w4, const float* __restrict__ g4, const float* __restrict__ b4,
    const float* __restrict__ m4, const float* __restrict__ v4, signed char* __restrict__ s4w,
    float* __restrict__ s4sf, float* __restrict__ s4bf) {
    const int bid = blockIdx.x;
    const float *w, *g, *b, *m, *v;
    signed char* wstg;
    float *wsf, *bfv;
    int I, KHW, OCP, GPT, o;
    if (bid < 448) {
        w = w1; g = g1; b = b1; m = m1; v = v1; wstg = s1w; wsf = s1sf; bfv = s1bf;
        I = 384; KHW = 1; OCP = 512; GPT = 24; o = bid;
    } else if (bid < 832) {
        w = w2; g = g2; b = b2; m = m2; v = v2; wstg = s2w; wsf = s2sf; bfv = s2bf;
        I = 448; KHW = 9; OCP = 384; GPT = 28; o = bid - 448;
    } else if (bid < 1216) {
        w = w3; g = g3; b = b3; m = m3; v = v3; wstg = s3w; wsf = s3sf; bfv = s3bf;
        I = 384; KHW = 3; OCP = 384; GPT = 24; o = bid - 832;
    } else {
        w = w4; g = g4; b = b4; m = m4; v = v4; wstg = s4w; wsf = s4sf; bfv = s4bf;
        I = 384; KHW = 3; OCP = 384; GPT = 24; o = bid - 1216;
    }
    const int E = I * KHW;
    __shared__ float red[256];
    const float std_ = sqrtf(v[o] + 1e-5f);
    const float fac = g[o] / std_;
    float lm = 0.f;
    for (int e = threadIdx.x; e < E; e += 256)
        lm = fmaxf(lm, fabsf(w[(size_t)o * E + e] * fac));
    red[threadIdx.x] = lm;
    __syncthreads();
    for (int s = 128; s > 0; s >>= 1) {
        if (threadIdx.x < s) red[threadIdx.x] = fmaxf(red[threadIdx.x], red[threadIdx.x + s]);
        __syncthreads();
    }
    const float w_sf = red[0] / NLVL;
    for (int e = threadIdx.x; e < E; e += 256) {
        const float wf = w[(size_t)o * E + e] * fac;
        float q = rintf(wf / w_sf);
        q = fminf(fmaxf(q, -128.f), 127.f);
        const int i = e / KHW;          // cin
        const int r = e - i * KHW;      // tap
        wstg[((size_t)(r * GPT + (i >> 4)) * OCP + o) * 16 + (i & 15)] = (signed char)q;
    }
    if (threadIdx.x == 0) {
        wsf[o] = w_sf;
        bfv[o] = b[o] - g[o] * m[o] / std_;
    }
}

// -------- int8 MFMA implicit-GEMM conv: 128pos x 128oc, NO LDS ---------------
// Split accumulators (accE/accO): 8 independent MFMA chains per wave (round-14
// chain-latency hypothesis). csf/bq computed inline from wsf/bf + scal[sidx].
// Output fp32 slab [coff16 + c16][NPOS][16].
template <int CINP, int COUT, int OCP, int KH, int KW, int PH, int PW>
__global__ __launch_bounds__(256) void qconv_mfma(
    const signed char* __restrict__ xin, const signed char* __restrict__ wstg,
    const float* __restrict__ wsf, const float* __restrict__ bfv,
    const float* __restrict__ scal, int sidx,
    float* __restrict__ yout, float* __restrict__ amax_slot,
    const signed char* __restrict__ zero16, int coff16) {
    constexpr int KCN = CINP / 64;
    constexpr int GPT = CINP / 16;
    constexpr int NKT = KH * KW * KCN;
    constexpr int NOC = OCP / 128;
    constexpr int NPB = 145;
    __shared__ float red[256];

    const int tid = threadIdx.x;
    const int lane = tid & 63;
    const int wid = tid >> 6;
    const int l31 = lane & 31;
    const int lh = lane >> 5;

    const int wgid = swz_wg(blockIdx.x, NPB * NOC);
    const int pb = wgid / NOC;
    const int ob = wgid - pb * NOC;
    const int p_blk = pb * 128;
    const int oc_blk = ob * 128;

    int pn[2], ph_[2], pw_[2];
    bool prowok[2];
#pragma unroll
    for (int it = 0; it < 2; ++it) {
        const int myp = p_blk + (wid >> 1) * 64 + it * 32 + l31;
        prowok[it] = myp < NPOS;
        const int pc = prowok[it] ? myp : 0;
        pn[it] = pc / 289;
        const int hw = pc - pn[it] * 289;
        ph_[it] = hw / 17;
        pw_[it] = hw - ph_[it] * 17;
    }
    const int oc_col0 = oc_blk + (wid & 1) * 64 + l31;

    auto loadA = [&](int kt, v4i (&a)[2][2]) {
        const int tap = kt / KCN;
        const int kc = kt - tap * KCN;
        const int kh = tap / KW;
        const int kw = tap - kh * KW;
#pragma unroll
        for (int it = 0; it < 2; ++it) {
            const int ih = ph_[it] + kh - PH;
            const int iw = pw_[it] + kw - PW;
            const bool ok = prowok[it] & ((unsigned)ih < 17u) & ((unsigned)iw < 17u);
            const int spos = pn[it] * 289 + ih * 17 + iw;
#pragma unroll
            for (int ks = 0; ks < 2; ++ks) {
                const signed char* p =
                    ok ? xin + ((size_t)((kc * 4 + ks * 2 + lh) * NPOS + spos)) * 16 : zero16;
                a[ks][it] = *(const v4i*)p;
            }
        }
    };
    auto loadB = [&](int kt, v4i (&b)[2][2]) {
        const int tap = kt / KCN;
        const int kc = kt - tap * KCN;
        const signed char* base =
            wstg + ((size_t)(tap * GPT + kc * 4 + lh) * OCP + oc_col0) * 16;
        b[0][0] = *(const v4i*)(base);
        b[0][1] = *(const v4i*)(base + 32 * 16);
        b[1][0] = *(const v4i*)(base + (size_t)2 * OCP * 16);
        b[1][1] = *(const v4i*)(base + (size_t)2 * OCP * 16 + 32 * 16);
    };

    v16i accE[2][2] = {}, accO[2][2] = {};  // split: 8 independent chains

    auto compute = [&](const v4i (&a)[2][2], const v4i (&b)[2][2]) {
        accE[0][0] = __builtin_amdgcn_mfma_i32_32x32x32_i8(a[0][0], b[0][0], accE[0][0], 0, 0, 0);
        accE[0][1] = __builtin_amdgcn_mfma_i32_32x32x32_i8(a[0][0], b[0][1], accE[0][1], 0, 0, 0);
        accE[1][0] = __builtin_amdgcn_mfma_i32_32x32x32_i8(a[0][1], b[0][0], accE[1][0], 0, 0, 0);
        accE[1][1] = __builtin_amdgcn_mfma_i32_32x32x32_i8(a[0][1], b[0][1], accE[1][1], 0, 0, 0);
        accO[0][0] = __builtin_amdgcn_mfma_i32_32x32x32_i8(a[1][0], b[1][0], accO[0][0], 0, 0, 0);
        accO[0][1] = __builtin_amdgcn_mfma_i32_32x32x32_i8(a[1][0], b[1][1], accO[0][1], 0, 0, 0);
        accO[1][0] = __builtin_amdgcn_mfma_i32_32x32x32_i8(a[1][1], b[1][0], accO[1][0], 0, 0, 0);
        accO[1][1] = __builtin_amdgcn_mfma_i32_32x32x32_i8(a[1][1], b[1][1], accO[1][1], 0, 0, 0);
    };

    v4i aA[2][2], bA[2][2], aB[2][2], bB[2][2];
    loadA(0, aA);
    loadB(0, bA);
    for (int kt = 0; kt < NKT; kt += 2) {
        if (kt + 1 < NKT) {
            loadA(kt + 1, aB);
            loadB(kt + 1, bB);
        }
        compute(aA, bA);
        if (kt + 1 < NKT) {
            if (kt + 2 < NKT) {
                loadA(kt + 2, aA);
                loadB(kt + 2, bA);
            }
            compute(aB, bB);
        }
    }

    // epilogue: csf/bq inline, bias + relu + scale, amax, slab store
    const float a_sf = scal[sidx] / NLVL;
    float csf[2];
    int bb[2], ocv[2];
#pragma unroll
    for (int jt = 0; jt < 2; ++jt) {
        const int oc = oc_blk + (wid & 1) * 64 + jt * 32 + l31;
        ocv[jt] = oc;
        const bool real = oc < COUT;
        const float wsfv = real ? wsf[oc] : 0.f;
        csf[jt] = a_sf * wsfv;
        bb[jt] = real ? (int)rintf(bfv[oc] / csf[jt]) : 0;
    }
    float lm = 0.f;
#pragma unroll
    for (int it = 0; it < 2; ++it) {
#pragma unroll
        for (int reg = 0; reg < 16; ++reg) {
            const int prow_o =
                p_blk + (wid >> 1) * 64 + it * 32 + (reg & 3) + 8 * (reg >> 2) + 4 * lh;
            const bool pok = prow_o < NPOS;
#pragma unroll
            for (int jt = 0; jt < 2; ++jt) {
                int t2 = accE[it][jt][reg] + accO[it][jt][reg] + bb[jt];
                t2 = t2 > 0 ? t2 : 0;
                const float v2 = csf[jt] * (float)t2;
                if (pok && ocv[jt] < COUT) {
                    lm = fmaxf(lm, v2);
                    yout[((size_t)(coff16 + (ocv[jt] >> 4)) * NPOS + prow_o) * 16 +
                         (ocv[jt] & 15)] = v2;
                }
            }
        }
    }
    red[tid] = lm;
    __syncthreads();
    for (int s = 128; s > 0; s >>= 1) {
        if (tid < s) red[tid] = fmaxf(red[tid], red[tid + s]);
        __syncthreads();
    }
    if (tid == 0) atomicMax((unsigned int*)amax_slot, __float_as_uint(red[0]));
}

// -------- fused dual-branch conv: conv3 (1x3 pad w) + conv4 (3x1 pad h) ------
// Same 128x128 tile; 8 acc chains (4 per branch); one launch, one amax pass.
// Writes branch3 -> slabs 0..23, branch4 -> slabs 24..47 of fbuf.
__global__ __launch_bounds__(256) void qconv_dual(
    const signed char* __restrict__ xin, const signed char* __restrict__ wstg3,
    const signed char* __restrict__ wstg4,
    const float* __restrict__ wsf3, const float* __restrict__ bf3,
    const float* __restrict__ wsf4, const float* __restrict__ bf4,
    const float* __restrict__ scal, int sidx,
    float* __restrict__ yout, float* __restrict__ amax_slot,
    const signed char* __restrict__ zero16) {
    constexpr int KCN = 6;     // 384 / 64
    constexpr int GPT = 24;    // 384 / 16
    constexpr int OCP = 384;
    constexpr int NKT = 3 * KCN;
    constexpr int NOC = 3;
    constexpr int NPB = 145;
    __shared__ float red[256];

    const int tid = threadIdx.x;
    const int lane = tid & 63;
    const int wid = tid >> 6;
    const int l31 = lane & 31;
    const int lh = lane >> 5;

    const int wgid = swz_wg(blockIdx.x, NPB * NOC);
    const int pb = wgid / NOC;
    const int ob = wgid - pb * NOC;
    const int p_blk = pb * 128;
    const int oc_blk = ob * 128;

    int pn[2], ph_[2], pw_[2];
    bool prowok[2];
#pragma unroll
    for (int it = 0; it < 2; ++it) {
        const int myp = p_blk + (wid >> 1) * 64 + it * 32 + l31;
        prowok[it] = myp < NPOS;
        const int pc = prowok[it] ? myp : 0;
        pn[it] = pc / 289;
        const int hw = pc - pn[it] * 289;
        ph_[it] = hw / 17;
        pw_[it] = hw - ph_[it] * 17;
    }
    const int oc_col0 = oc_blk + (wid & 1) * 64 + l31;

    // generic A load at spatial offset (dh, dw)
    auto loadA = [&](int dh, int dw, int kc, v4i (&a)[2][2]) {
#pragma unroll
        for (int it = 0; it < 2; ++it) {
            const int ih = ph_[it] + dh;
            const int iw = pw_[it] + dw;
            const bool ok = prowok[it] & ((unsigned)ih < 17u) & ((unsigned)iw < 17u);
            const int spos = pn[it] * 289 + ih * 17 + iw;
#pragma unroll
            for (int ks = 0; ks < 2; ++ks) {
                const signed char* p =
                    ok ? xin + ((size_t)((kc * 4 + ks * 2 + lh) * NPOS + spos)) * 16 : zero16;
                a[ks][it] = *(const v4i*)p;
            }
        }
    };
    auto loadB = [&](const signed char* wstg, int tap, int kc, v4i (&b)[2][2]) {
        const signed char* base =
            wstg + ((size_t)(tap * GPT + kc * 4 + lh) * OCP + oc_col0) * 16;
        b[0][0] = *(const v4i*)(base);
        b[0][1] = *(const v4i*)(base + 32 * 16);
        b[1][0] = *(const v4i*)(base + (size_t)2 * OCP * 16);
        b[1][1] = *(const v4i*)(base + (size_t)2 * OCP * 16 + 32 * 16);
    };

    v16i acc3[2][2] = {}, acc4[2][2] = {};

    auto compute = [&](v16i (&acc)[2][2], const v4i (&a)[2][2], const v4i (&b)[2][2]) {
#pragma unroll
        for (int ks = 0; ks < 2; ++ks) {
            acc[0][0] = __builtin_amdgcn_mfma_i32_32x32x32_i8(a[ks][0], b[ks][0], acc[0][0], 0, 0, 0);
            acc[0][1] = __builtin_amdgcn_mfma_i32_32x32x32_i8(a[ks][0], b[ks][1], acc[0][1], 0, 0, 0);
            acc[1][0] = __builtin_amdgcn_mfma_i32_32x32x32_i8(a[ks][1], b[ks][0], acc[1][0], 0, 0, 0);
            acc[1][1] = __builtin_amdgcn_mfma_i32_32x32x32_i8(a[ks][1], b[ks][1], acc[1][1], 0, 0, 0);
        }
    };

    for (int kt = 0; kt < NKT; ++kt) {
        const int tap = kt / KCN;
        const int kc = kt - tap * KCN;
        v4i a3[2][2], a4[2][2], b3[2][2], b4[2][2];
        loadA(0, tap - 1, kc, a3);       // conv3: 1x3, pad w
        loadA(tap - 1, 0, kc, a4);       // conv4: 3x1, pad h
        loadB(wstg3, tap, kc, b3);
        loadB(wstg4, tap, kc, b4);
        compute(acc3, a3, b3);
        compute(acc4, a4, b4);
    }

    // epilogue: both branches, shared amax
    const float a_sf = scal[sidx] / NLVL;
    float csf3[2], csf4[2];
    int bb3[2], bb4[2], ocv[2];
#pragma unroll
    for (int jt = 0; jt < 2; ++jt) {
        const int oc = oc_blk + (wid & 1) * 64 + jt * 32 + l31;
        ocv[jt] = oc;
        csf3[jt] = a_sf * wsf3[oc];
        bb3[jt] = (int)rintf(bf3[oc] / csf3[jt]);
        csf4[jt] = a_sf * wsf4[oc];
        bb4[jt] = (int)rintf(bf4[oc] / csf4[jt]);
    }
    float lm = 0.f;
#pragma unroll
    for (int it = 0; it < 2; ++it) {
#pragma unroll
        for (int reg = 0; reg < 16; ++reg) {
            const int prow_o =
                p_blk + (wid >> 1) * 64 + it * 32 + (reg & 3) + 8 * (reg >> 2) + 4 * lh;
            const bool pok = prow_o < NPOS;
#pragma unroll
            for (int jt = 0; jt < 2; ++jt) {
                int t3 = acc3[it][jt][reg] + bb3[jt];
                t3 = t3 > 0 ? t3 : 0;
                const float v3v = csf3[jt] * (float)t3;
                int t4 = acc4[it][jt][reg] + bb4[jt];
                t4 = t4 > 0 ? t4 : 0;
                const float v4v = csf4[jt] * (float)t4;
                if (pok) {
                    lm = fmaxf(lm, fmaxf(v3v, v4v));
                    const size_t sl = (size_t)(ocv[jt] >> 4);
                    yout[(sl * NPOS + prow_o) * 16 + (ocv[jt] & 15)] = v3v;
                    yout[(((size_t)24 + sl) * NPOS + prow_o) * 16 + (ocv[jt] & 15)] = v4v;
                }
            }
        }
    }
    red[tid] = lm;
    __syncthreads();
    for (int s = 128; s > 0; s >>= 1) {
        if (tid < s) red[tid] = fmaxf(red[tid], red[tid + s]);
        __syncthreads();
    }
    if (tid == 0) atomicMax((unsigned int*)amax_slot, __float_as_uint(red[0]));
}

// -------- requantize fp32 slab -> int8 slab (both linear) -------------------
__global__ __launch_bounds__(256) void requant_kernel(const float* __restrict__ f,
                                                      signed char* __restrict__ q,
                                                      const float* __restrict__ scal,
                                                      int idx, int nvec) {
    const float s = scal[idx] / NLVL;
    for (int i = blockIdx.x * 256 + threadIdx.x; i < nvec; i += gridDim.x * 256) {
        const float4 v = ((const float4*)f)[i];
        const int b0 = (int)fminf(fmaxf(rintf(v.x / s), -128.f), 127.f);
        const int b1 = (int)fminf(fmaxf(rintf(v.y / s), -128.f), 127.f);
        const int b2 = (int)fminf(fmaxf(rintf(v.z / s), -128.f), 127.f);
        const int b3 = (int)fminf(fmaxf(rintf(v.w / s), -128.f), 127.f);
        ((unsigned int*)q)[i] =
            (b0 & 0xff) | ((b1 & 0xff) << 8) | ((b2 & 0xff) << 16) | ((b3 & 0xff) << 24);
    }
}

// -------- final: slab fp32 [48][NPOS][16] -> requant -> NCHW d_out -----------
__global__ __launch_bounds__(256) void transpose_requant_kernel(
    const float* __restrict__ f, float* __restrict__ out,
    const float* __restrict__ scal, int idx) {
    __shared__ float tile[64][65];
    const float s = scal[idx] / NLVL;
    const int tid = threadIdx.x;
    const int w = tid >> 6, l = tid & 63;
    const int pt = blockIdx.x % 289, ct = blockIdx.x / 289;  // pos-tile, ch-tile
    const int pos0 = pt * 64, c0 = ct * 64;
    const int slab = ct * 4 + w;  // this wave's 16-ch slab
#pragma unroll
    for (int j = 0; j < 4; ++j) {
        const int p = (l >> 2) + j * 16;  // 0..63
        const int co = (l & 3) * 4;       // 0,4,8,12
        const float4 v = *(const float4*)&f[((size_t)slab * NPOS + pos0 + p) * 16 + co];
        tile[p][w * 16 + co + 0] = v.x;
        tile[p][w * 16 + co + 1] = v.y;
        tile[p][w * 16 + co + 2] = v.z;
        tile[p][w * 16 + co + 3] = v.w;
    }
    __syncthreads();
    const int pos = pos0 + l;
    const int n = pos / 289;
    const int hw = pos - n * 289;
#pragma unroll
    for (int k = 0; k < 16; ++k) {
        const int c = c0 + w * 16 + k;
        float v = tile[l][w * 16 + k];
        v = fminf(fmaxf(rintf(v / s), -128.f), 127.f) * s;
        out[((size_t)(n * 768 + c)) * 289 + hw] = v;
    }
}

extern "C" void kernel_launch(void* const* d_in, const int* in_sizes, int n_in,
                              void* d_out, int out_size, void* d_ws, size_t ws_size,
                              hipStream_t stream) {
    const float* x  = (const float*)d_in[0];
    const float* w1 = (const float*)d_in[1];
    const float* g1 = (const float*)d_in[2];
    const float* b1 = (const float*)d_in[3];
    const float* m1 = (const float*)d_in[4];
    const float* v1 = (const float*)d_in[5];
    const float* w2 = (const float*)d_in[6];
    const float* g2 = (const float*)d_in[7];
    const float* b2 = (const float*)d_in[8];
    const float* m2 = (const float*)d_in[9];
    const float* v2 = (const float*)d_in[10];
    const float* w3 = (const float*)d_in[11];
    const float* g3 = (const float*)d_in[12];
    const float* b3 = (const float*)d_in[13];
    const float* m3 = (const float*)d_in[14];
    const float* v3 = (const float*)d_in[15];
    const float* w4 = (const float*)d_in[16];
    const float* g4 = (const float*)d_in[17];
    const float* b4 = (const float*)d_in[18];
    const float* m4 = (const float*)d_in[19];
    const float* v4 = (const float*)d_in[20];
    float* out = (float*)d_out;
    char* ws = (char*)d_ws;

    size_t off = 0;
    auto take = [&](size_t bytes) {
        char* p = ws + off;
        off = (off + bytes + 255) & ~(size_t)255;
        return p;
    };
    float* scal = (float*)take(64);  // amax slots 0..3; bytes 32..47 = zero16
    const signed char* zero16 = (const signed char*)(scal + 8);
    signed char* wstg1 = (signed char*)take((size_t)24 * 512 * 16);   // OCP=512 stride
    float* sf1 = (float*)take(448 * 4);
    float* bf1 = (float*)take(448 * 4);
    signed char* wstg2 = (signed char*)take((size_t)9 * 28 * 384 * 16);
    float* sf2 = (float*)take(384 * 4);
    float* bf2 = (float*)take(384 * 4);
    signed char* wstg3 = (signed char*)take((size_t)3 * 24 * 384 * 16);
    float* sf3 = (float*)take(384 * 4);
    float* bf3 = (float*)take(384 * 4);
    signed char* wstg4 = (signed char*)take((size_t)3 * 24 * 384 * 16);
    float* sf4 = (float*)take(384 * 4);
    float* bf4 = (float*)take(384 * 4);
    signed char* n0 = (signed char*)take((size_t)24 * NPOS * 16);   // slab int8 384ch
    signed char* q1 = (signed char*)take((size_t)28 * NPOS * 16);   // slab int8 448ch
    signed char* q2 = (signed char*)take((size_t)24 * NPOS * 16);   // slab int8 384ch
    float* fbuf = (float*)take((size_t)48 * NPOS * 16 * 4);         // fp32 slab, 768ch

    hipMemsetAsync(scal, 0, 64, stream);
    hipMemsetAsync(wstg1, 0, (size_t)24 * 512 * 16, stream);  // pad oc cols 448..511

    // weight prep (all 4 stages, no activation dependency)
    wq_kernel<<<1600, 256, 0, stream>>>(w1, g1, b1, m1, v1, wstg1, sf1, bf1,
                                        w2, g2, b2, m2, v2, wstg2, sf2, bf2,
                                        w3, g3, b3, m3, v3, wstg3, sf3, bf3,
                                        w4, g4, b4, m4, v4, wstg4, sf4, bf4);

    // stage 0: quantize input
    amax_abs_kernel<<<1024, 256, 0, stream>>>(x, 64 * 384 * 289, scal + 0);
    quant_x_kernel<<<289, 256, 0, stream>>>(x, n0, scal);

    // conv1: 1x1, 384->448 (OCP stride 512, pad cols zeroed)
    qconv_mfma<384, 448, 512, 1, 1, 0, 0>
        <<<145 * 4, 256, 0, stream>>>(n0, wstg1, sf1, bf1, scal, 0, fbuf, scal + 1, zero16, 0);
    requant_kernel<<<2048, 256, 0, stream>>>(fbuf, q1, scal, 1, 28 * NPOS * 16 / 4);

    // conv2: 3x3 pad 1, 448->384 (true K=448)
    qconv_mfma<448, 384, 384, 3, 3, 1, 1>
        <<<145 * 3, 256, 0, stream>>>(q1, wstg2, sf2, bf2, scal, 1, fbuf, scal + 2, zero16, 0);
    requant_kernel<<<2048, 256, 0, stream>>>(fbuf, q2, scal, 2, 24 * NPOS * 16 / 4);

    // fused branches: conv3 (1x3) + conv4 (3x1) -> slabs 0..23 / 24..47
    qconv_dual<<<145 * 3, 256, 0, stream>>>(q2, wstg3, wstg4, sf3, bf3, sf4, bf4,
                                            scal, 2, fbuf, scal + 3, zero16);

    // final: slab -> requant -> NCHW concat output (coalesced both sides)
    transpose_requant_kernel<<<289 * 12, 256, 0, stream>>>(fbuf, out, scal, 3);
}

// Round 16
// 213.980 us; speedup vs baseline: 1.1914x; 1.1914x over previous
//
#include <hip/hip_runtime.h>
#include <stdint.h>

#define NLVL 127.0f
#define NPOS (64 * 289)

typedef int v4i __attribute__((ext_vector_type(4)));
typedef int v16i __attribute__((ext_vector_type(16)));
typedef unsigned int uint;

// bijective XCD-aware swizzle (m204): xcd = bid%8 gets a contiguous work range
__device__ __forceinline__ int swz_wg(int bid, int nwg) {
    const int q = nwg >> 3, r = nwg & 7;
    const int xcd = bid & 7;
    const int base = xcd < r ? xcd * (q + 1) : r * (q + 1) + (xcd - r) * q;
    return base + (bid >> 3);
}

// -------- global abs-max reduction (atomicMax on float bits; values >= 0) ----
__global__ __launch_bounds__(256) void amax_abs_kernel(const float* __restrict__ x,
                                                       int n, float* __restrict__ slot) {
    __shared__ float red[256];
    float lm = 0.f;
    for (int i = blockIdx.x * 256 + threadIdx.x; i < n; i += gridDim.x * 256)
        lm = fmaxf(lm, fabsf(x[i]));
    red[threadIdx.x] = lm;
    __syncthreads();
    for (int s = 128; s > 0; s >>= 1) {
        if (threadIdx.x < s) red[threadIdx.x] = fmaxf(red[threadIdx.x], red[threadIdx.x + s]);
        __syncthreads();
    }
    if (threadIdx.x == 0) atomicMax((unsigned int*)slot, __float_as_uint(red[0]));
}

// -------- quantize input x: NCHW fp32 -> slab int8 [c16][NPOS][16] -----------
__global__ __launch_bounds__(256) void quant_x_kernel(const float* __restrict__ x,
                                                      signed char* __restrict__ n0,
                                                      const float* __restrict__ scal) {
    __shared__ uint t32[64][97];
    const float s = scal[0] / NLVL;
    const int tid = threadIdx.x;
    const int pi = tid & 63;
    const int pos = blockIdx.x * 64 + pi;
    const int n = pos / 289;
    const int hw = pos - n * 289;
    const float* xb = x + (size_t)n * 384 * 289 + hw;
    for (int cq = tid >> 6; cq < 96; cq += 4) {
        uint pk = 0;
#pragma unroll
        for (int k = 0; k < 4; ++k) {
            const float f = xb[(size_t)(cq * 4 + k) * 289];
            float q = rintf(f / s);
            q = fminf(fmaxf(q, -128.f), 127.f);
            pk |= ((uint)((int)q & 0xff)) << (8 * k);
        }
        t32[pi][cq] = pk;
    }
    __syncthreads();
    for (int k = 0; k < 6; ++k) {
        const int c16 = (tid >> 6) + k * 4;  // 0..23
        uint4 v;
        v.x = t32[pi][c16 * 4 + 0];
        v.y = t32[pi][c16 * 4 + 1];
        v.z = t32[pi][c16 * 4 + 2];
        v.w = t32[pi][c16 * 4 + 3];
        *(uint4*)&n0[((size_t)c16 * NPOS + pos) * 16] = v;
    }
}

// -------- merged weight prep: all 4 stages, NO scal dependency ----------------
// quantizes folded weights into wstg [r*GPT + (i>>4)][OCP][16]; stores per-oc
// w_sf and folded bias bf (csf/bq computed inside the conv epilogue).
__global__ __launch_bounds__(256) void wq_kernel(
    const float* __restrict__ w1, const float* __restrict__ g1, const float* __restrict__ b1,
    const float* __restrict__ m1, const float* __restrict__ v1, signed char* __restrict__ s1w,
    float* __restrict__ s1sf, float* __restrict__ s1bf,
    const float* __restrict__ w2, const float* __restrict__ g2, const float* __restrict__ b2,
    const float* __restrict__ m2, const float* __restrict__ v2, signed char* __restrict__ s2w,
    float* __restrict__ s2sf, float* __restrict__ s2bf,
    const float* __restrict__ w3, const float* __restrict__ g3, const float* __restrict__ b3,
    const float* __restrict__ m3, const float* __restrict__ v3, signed char* __restrict__ s3w,
    float* __restrict__ s3sf, float* __restrict__ s3bf,
    const float* __restrict__ w4, const float* __restrict__ g4, const float* __restrict__ b4,
    const float* __restrict__ m4, const float* __restrict__ v4, signed char* __restrict__ s4w,
    float* __restrict__ s4sf, float* __restrict__ s4bf) {
    const int bid = blockIdx.x;
    const float *w, *g, *b, *m, *v;
    signed char* wstg;
    float *wsf, *bfv;
    int I, KHW, OCP, GPT, o;
    if (bid < 448) {
        w = w1; g = g1; b = b1; m = m1; v = v1; wstg = s1w; wsf = s1sf; bfv = s1bf;
        I = 384; KHW = 1; OCP = 512; GPT = 24; o = bid;
    } else if (bid < 832) {
        w = w2; g = g2; b = b2; m = m2; v = v2; wstg = s2w; wsf = s2sf; bfv = s2bf;
        I = 448; KHW = 9; OCP = 384; GPT = 28; o = bid - 448;
    } else if (bid < 1216) {
        w = w3; g = g3; b = b3; m = m3; v = v3; wstg = s3w; wsf = s3sf; bfv = s3bf;
        I = 384; KHW = 3; OCP = 384; GPT = 24; o = bid - 832;
    } else {
        w = w4; g = g4; b = b4; m = m4; v = v4; wstg = s4w; wsf = s4sf; bfv = s4bf;
        I = 384; KHW = 3; OCP = 384; GPT = 24; o = bid - 1216;
    }
    const int E = I * KHW;
    __shared__ float red[256];
    const float std_ = sqrtf(v[o] + 1e-5f);
    const float fac = g[o] / std_;
    float lm = 0.f;
    for (int e = threadIdx.x; e < E; e += 256)
        lm = fmaxf(lm, fabsf(w[(size_t)o * E + e] * fac));
    red[threadIdx.x] = lm;
    __syncthreads();
    for (int s = 128; s > 0; s >>= 1) {
        if (threadIdx.x < s) red[threadIdx.x] = fmaxf(red[threadIdx.x], red[threadIdx.x + s]);
        __syncthreads();
    }
    const float w_sf = red[0] / NLVL;
    for (int e = threadIdx.x; e < E; e += 256) {
        const float wf = w[(size_t)o * E + e] * fac;
        float q = rintf(wf / w_sf);
        q = fminf(fmaxf(q, -128.f), 127.f);
        const int i = e / KHW;          // cin
        const int r = e - i * KHW;      // tap
        wstg[((size_t)(r * GPT + (i >> 4)) * OCP + o) * 16 + (i & 15)] = (signed char)q;
    }
    if (threadIdx.x == 0) {
        wsf[o] = w_sf;
        bfv[o] = b[o] - g[o] * m[o] / std_;
    }
}

// -------- int8 MFMA implicit-GEMM conv: 128pos x 128oc, NO LDS, depth-3 ILP --
// Round-14 proven loop (single acc[2][2], depth-3 named-set rotation).
// csf/bq computed inline from wsf/bf + scal[sidx]. Output fp32 slab.
template <int CINP, int COUT, int OCP, int KH, int KW, int PH, int PW>
__global__ __launch_bounds__(256) void qconv_mfma(
    const signed char* __restrict__ xin, const signed char* __restrict__ wstg,
    const float* __restrict__ wsf, const float* __restrict__ bfv,
    const float* __restrict__ scal, int sidx,
    float* __restrict__ yout, float* __restrict__ amax_slot,
    const signed char* __restrict__ zero16, int coff16) {
    constexpr int KCN = CINP / 64;
    constexpr int GPT = CINP / 16;
    constexpr int NKT = KH * KW * KCN;     // 63 / 6 / 18 — all % 3 == 0
    static_assert(NKT % 3 == 0, "depth-3 rotation needs NKT % 3 == 0");
    constexpr int NOC = OCP / 128;
    constexpr int NPB = 145;
    __shared__ float red[256];

    const int tid = threadIdx.x;
    const int lane = tid & 63;
    const int wid = tid >> 6;
    const int l31 = lane & 31;
    const int lh = lane >> 5;

    const int wgid = swz_wg(blockIdx.x, NPB * NOC);
    const int pb = wgid / NOC;
    const int ob = wgid - pb * NOC;
    const int p_blk = pb * 128;
    const int oc_blk = ob * 128;

    int pn[2], ph_[2], pw_[2];
    bool prowok[2];
#pragma unroll
    for (int it = 0; it < 2; ++it) {
        const int myp = p_blk + (wid >> 1) * 64 + it * 32 + l31;
        prowok[it] = myp < NPOS;
        const int pc = prowok[it] ? myp : 0;
        pn[it] = pc / 289;
        const int hw = pc - pn[it] * 289;
        ph_[it] = hw / 17;
        pw_[it] = hw - ph_[it] * 17;
    }
    const int oc_col0 = oc_blk + (wid & 1) * 64 + l31;

    auto loadA = [&](int kt, v4i (&a)[2][2]) {
        const int tap = kt / KCN;
        const int kc = kt - tap * KCN;
        const int kh = tap / KW;
        const int kw = tap - kh * KW;
#pragma unroll
        for (int it = 0; it < 2; ++it) {
            const int ih = ph_[it] + kh - PH;
            const int iw = pw_[it] + kw - PW;
            const bool ok = prowok[it] & ((unsigned)ih < 17u) & ((unsigned)iw < 17u);
            const int spos = pn[it] * 289 + ih * 17 + iw;
#pragma unroll
            for (int ks = 0; ks < 2; ++ks) {
                const signed char* p =
                    ok ? xin + ((size_t)((kc * 4 + ks * 2 + lh) * NPOS + spos)) * 16 : zero16;
                a[ks][it] = *(const v4i*)p;
            }
        }
    };
    auto loadB = [&](int kt, v4i (&b)[2][2]) {
        const int tap = kt / KCN;
        const int kc = kt - tap * KCN;
        const signed char* base =
            wstg + ((size_t)(tap * GPT + kc * 4 + lh) * OCP + oc_col0) * 16;
        b[0][0] = *(const v4i*)(base);
        b[0][1] = *(const v4i*)(base + 32 * 16);
        b[1][0] = *(const v4i*)(base + (size_t)2 * OCP * 16);
        b[1][1] = *(const v4i*)(base + (size_t)2 * OCP * 16 + 32 * 16);
    };

    v16i acc[2][2] = {};

    auto compute = [&](const v4i (&a)[2][2], const v4i (&b)[2][2]) {
#pragma unroll
        for (int ks = 0; ks < 2; ++ks) {
            acc[0][0] = __builtin_amdgcn_mfma_i32_32x32x32_i8(a[ks][0], b[ks][0], acc[0][0], 0, 0, 0);
            acc[0][1] = __builtin_amdgcn_mfma_i32_32x32x32_i8(a[ks][0], b[ks][1], acc[0][1], 0, 0, 0);
            acc[1][0] = __builtin_amdgcn_mfma_i32_32x32x32_i8(a[ks][1], b[ks][0], acc[1][0], 0, 0, 0);
            acc[1][1] = __builtin_amdgcn_mfma_i32_32x32x32_i8(a[ks][1], b[ks][1], acc[1][1], 0, 0, 0);
        }
    };

    // three named register sets (rule 20: all indices static)
    v4i aA[2][2], bA[2][2], aB[2][2], bB[2][2], aC[2][2], bC[2][2];
    loadA(0, aA); loadB(0, bA);
    loadA(1, aB); loadB(1, bB);
    loadA(2, aC); loadB(2, bC);
    for (int kt = 0; kt < NKT; kt += 3) {
        compute(aA, bA);
        if (kt + 3 < NKT) { loadA(kt + 3, aA); loadB(kt + 3, bA); }
        compute(aB, bB);
        if (kt + 4 < NKT) { loadA(kt + 4, aB); loadB(kt + 4, bB); }
        compute(aC, bC);
        if (kt + 5 < NKT) { loadA(kt + 5, aC); loadB(kt + 5, bC); }
    }

    // epilogue: csf/bq inline, bias + relu + scale, amax, slab store
    const float a_sf = scal[sidx] / NLVL;
    float csf[2];
    int bb[2], ocv[2];
#pragma unroll
    for (int jt = 0; jt < 2; ++jt) {
        const int oc = oc_blk + (wid & 1) * 64 + jt * 32 + l31;
        ocv[jt] = oc;
        const bool real = oc < COUT;
        const float wsfv = real ? wsf[oc] : 0.f;
        csf[jt] = a_sf * wsfv;
        bb[jt] = real ? (int)rintf(bfv[oc] / csf[jt]) : 0;
    }
    float lm = 0.f;
#pragma unroll
    for (int it = 0; it < 2; ++it) {
#pragma unroll
        for (int reg = 0; reg < 16; ++reg) {
            const int prow_o =
                p_blk + (wid >> 1) * 64 + it * 32 + (reg & 3) + 8 * (reg >> 2) + 4 * lh;
            const bool pok = prow_o < NPOS;
#pragma unroll
            for (int jt = 0; jt < 2; ++jt) {
                int t2 = acc[it][jt][reg] + bb[jt];
                t2 = t2 > 0 ? t2 : 0;
                const float v2 = csf[jt] * (float)t2;
                if (pok && ocv[jt] < COUT) {
                    lm = fmaxf(lm, v2);
                    yout[((size_t)(coff16 + (ocv[jt] >> 4)) * NPOS + prow_o) * 16 +
                         (ocv[jt] & 15)] = v2;
                }
            }
        }
    }
    red[tid] = lm;
    __syncthreads();
    for (int s = 128; s > 0; s >>= 1) {
        if (tid < s) red[tid] = fmaxf(red[tid], red[tid + s]);
        __syncthreads();
    }
    if (tid == 0) atomicMax((unsigned int*)amax_slot, __float_as_uint(red[0]));
}

// -------- requantize fp32 slab -> int8 slab (both linear) -------------------
__global__ __launch_bounds__(256) void requant_kernel(const float* __restrict__ f,
                                                      signed char* __restrict__ q,
                                                      const float* __restrict__ scal,
                                                      int idx, int nvec) {
    const float s = scal[idx] / NLVL;
    for (int i = blockIdx.x * 256 + threadIdx.x; i < nvec; i += gridDim.x * 256) {
        const float4 v = ((const float4*)f)[i];
        const int b0 = (int)fminf(fmaxf(rintf(v.x / s), -128.f), 127.f);
        const int b1 = (int)fminf(fmaxf(rintf(v.y / s), -128.f), 127.f);
        const int b2 = (int)fminf(fmaxf(rintf(v.z / s), -128.f), 127.f);
        const int b3 = (int)fminf(fmaxf(rintf(v.w / s), -128.f), 127.f);
        ((unsigned int*)q)[i] =
            (b0 & 0xff) | ((b1 & 0xff) << 8) | ((b2 & 0xff) << 16) | ((b3 & 0xff) << 24);
    }
}

// -------- final: slab fp32 [48][NPOS][16] -> requant -> NCHW d_out -----------
__global__ __launch_bounds__(256) void transpose_requant_kernel(
    const float* __restrict__ f, float* __restrict__ out,
    const float* __restrict__ scal, int idx) {
    __shared__ float tile[64][65];
    const float s = scal[idx] / NLVL;
    const int tid = threadIdx.x;
    const int w = tid >> 6, l = tid & 63;
    const int pt = blockIdx.x % 289, ct = blockIdx.x / 289;  // pos-tile, ch-tile
    const int pos0 = pt * 64, c0 = ct * 64;
    const int slab = ct * 4 + w;  // this wave's 16-ch slab
#pragma unroll
    for (int j = 0; j < 4; ++j) {
        const int p = (l >> 2) + j * 16;  // 0..63
        const int co = (l & 3) * 4;       // 0,4,8,12
        const float4 v = *(const float4*)&f[((size_t)slab * NPOS + pos0 + p) * 16 + co];
        tile[p][w * 16 + co + 0] = v.x;
        tile[p][w * 16 + co + 1] = v.y;
        tile[p][w * 16 + co + 2] = v.z;
        tile[p][w * 16 + co + 3] = v.w;
    }
    __syncthreads();
    const int pos = pos0 + l;
    const int n = pos / 289;
    const int hw = pos - n * 289;
#pragma unroll
    for (int k = 0; k < 16; ++k) {
        const int c = c0 + w * 16 + k;
        float v = tile[l][w * 16 + k];
        v = fminf(fmaxf(rintf(v / s), -128.f), 127.f) * s;
        out[((size_t)(n * 768 + c)) * 289 + hw] = v;
    }
}

extern "C" void kernel_launch(void* const* d_in, const int* in_sizes, int n_in,
                              void* d_out, int out_size, void* d_ws, size_t ws_size,
                              hipStream_t stream) {
    const float* x  = (const float*)d_in[0];
    const float* w1 = (const float*)d_in[1];
    const float* g1 = (const float*)d_in[2];
    const float* b1 = (const float*)d_in[3];
    const float* m1 = (const float*)d_in[4];
    const float* v1 = (const float*)d_in[5];
    const float* w2 = (const float*)d_in[6];
    const float* g2 = (const float*)d_in[7];
    const float* b2 = (const float*)d_in[8];
    const float* m2 = (const float*)d_in[9];
    const float* v2 = (const float*)d_in[10];
    const float* w3 = (const float*)d_in[11];
    const float* g3 = (const float*)d_in[12];
    const float* b3 = (const float*)d_in[13];
    const float* m3 = (const float*)d_in[14];
    const float* v3 = (const float*)d_in[15];
    const float* w4 = (const float*)d_in[16];
    const float* g4 = (const float*)d_in[17];
    const float* b4 = (const float*)d_in[18];
    const float* m4 = (const float*)d_in[19];
    const float* v4 = (const float*)d_in[20];
    float* out = (float*)d_out;
    char* ws = (char*)d_ws;

    size_t off = 0;
    auto take = [&](size_t bytes) {
        char* p = ws + off;
        off = (off + bytes + 255) & ~(size_t)255;
        return p;
    };
    float* scal = (float*)take(64);  // amax slots 0..3; bytes 32..47 = zero16
    const signed char* zero16 = (const signed char*)(scal + 8);
    signed char* wstg1 = (signed char*)take((size_t)24 * 512 * 16);   // OCP=512 stride
    float* sf1 = (float*)take(448 * 4);
    float* bf1 = (float*)take(448 * 4);
    signed char* wstg2 = (signed char*)take((size_t)9 * 28 * 384 * 16);
    float* sf2 = (float*)take(384 * 4);
    float* bf2 = (float*)take(384 * 4);
    signed char* wstg3 = (signed char*)take((size_t)3 * 24 * 384 * 16);
    float* sf3 = (float*)take(384 * 4);
    float* bf3 = (float*)take(384 * 4);
    signed char* wstg4 = (signed char*)take((size_t)3 * 24 * 384 * 16);
    float* sf4 = (float*)take(384 * 4);
    float* bf4 = (float*)take(384 * 4);
    signed char* n0 = (signed char*)take((size_t)24 * NPOS * 16);   // slab int8 384ch
    signed char* q1 = (signed char*)take((size_t)28 * NPOS * 16);   // slab int8 448ch
    signed char* q2 = (signed char*)take((size_t)24 * NPOS * 16);   // slab int8 384ch
    float* fbuf = (float*)take((size_t)48 * NPOS * 16 * 4);         // fp32 slab, 768ch

    hipMemsetAsync(scal, 0, 64, stream);
    hipMemsetAsync(wstg1, 0, (size_t)24 * 512 * 16, stream);  // pad oc cols 448..511

    // weight prep (all 4 stages, no activation dependency)
    wq_kernel<<<1600, 256, 0, stream>>>(w1, g1, b1, m1, v1, wstg1, sf1, bf1,
                                        w2, g2, b2, m2, v2, wstg2, sf2, bf2,
                                        w3, g3, b3, m3, v3, wstg3, sf3, bf3,
                                        w4, g4, b4, m4, v4, wstg4, sf4, bf4);

    // stage 0: quantize input
    amax_abs_kernel<<<1024, 256, 0, stream>>>(x, 64 * 384 * 289, scal + 0);
    quant_x_kernel<<<289, 256, 0, stream>>>(x, n0, scal);

    // conv1: 1x1, 384->448 (OCP stride 512, pad cols zeroed)
    qconv_mfma<384, 448, 512, 1, 1, 0, 0>
        <<<145 * 4, 256, 0, stream>>>(n0, wstg1, sf1, bf1, scal, 0, fbuf, scal + 1, zero16, 0);
    requant_kernel<<<2048, 256, 0, stream>>>(fbuf, q1, scal, 1, 28 * NPOS * 16 / 4);

    // conv2: 3x3 pad 1, 448->384 (true K=448)
    qconv_mfma<448, 384, 384, 3, 3, 1, 1>
        <<<145 * 3, 256, 0, stream>>>(q1, wstg2, sf2, bf2, scal, 1, fbuf, scal + 2, zero16, 0);
    requant_kernel<<<2048, 256, 0, stream>>>(fbuf, q2, scal, 2, 24 * NPOS * 16 / 4);

    // branches: conv3 (1x3) -> slabs 0..23, conv4 (3x1) -> slabs 24..47
    qconv_mfma<384, 384, 384, 1, 3, 0, 1>
        <<<145 * 3, 256, 0, stream>>>(q2, wstg3, sf3, bf3, scal, 2, fbuf, scal + 3, zero16, 0);
    qconv_mfma<384, 384, 384, 3, 1, 1, 0>
        <<<145 * 3, 256, 0, stream>>>(q2, wstg4, sf4, bf4, scal, 2, fbuf, scal + 3, zero16, 24);

    // final: slab -> requant -> NCHW concat output (coalesced both sides)
    transpose_requant_kernel<<<289 * 12, 256, 0, stream>>>(fbuf, out, scal, 3);
}